// Round 12
// baseline (672.823 us; speedup 1.0000x reference)
//
#include <hip/hip_runtime.h>
#include <hip/hip_bf16.h>
#include <hip/hip_cooperative_groups.h>

namespace cg = cooperative_groups;

// ---------------------------------------------------------------------------
// 3-layer GCN + global mean pool, MI355X — round 26: cooperative tail kernel
//
// R25: 232.9us; kernel-sum ~152us -> ~80us across 5 launch boundaries
// (~16us each); aggs pinned at the compulsory cross-XCD FETCH floor (83MB).
// R26 merges the dependent back-end chain (agg1@W2 -> agg2@W3 -> agg3+pool)
// into ONE hipLaunchCooperativeKernel with grid.sync() between phases:
// - grid sized by occupancy query (<=8 blocks/CU) -> co-residency guaranteed
// - dynamic work counters (atomicAdd per 16-node unit) -> HW-scheduler-like
//   load balance, no static-stride quantization tail
// - __threadfence() before each sync (G16 device-scope release)
// - phase bodies = R25 kernels verbatim -> numerics identical.
// 6 launches -> 4.
// ---------------------------------------------------------------------------

constexpr int NN   = 50000;   // nodes (divisible by 16)
constexpr int NE   = 800000;  // edges
constexpr int GG   = 512;     // graphs
constexpr int SLOT = 64;      // padded slots/node

constexpr int NBUCK  = (NN + 127) / 128;       // 391 buckets of 128 nodes
constexpr int BCAP   = 2560;                   // per-bucket capacity
constexpr int EPB    = 2048;                   // edges per binA block
constexpr int NBLK_A = (NE + EPB - 1) / EPB;   // 391 blocks
constexpr int NCTRL  = NBUCK + 2 * GG + 4;     // cursor + gstart + gend + wc[4]

using shortx8 = __attribute__((ext_vector_type(8))) short;   // 8 bf16 = 4 VGPRs
using f32x4   = __attribute__((ext_vector_type(4))) float;
using f32x2   = __attribute__((ext_vector_type(2))) float;

__device__ __forceinline__ unsigned short f2bf(float f) {
    __hip_bfloat16 h = __float2bfloat16(f);   // RNE
    return *(unsigned short*)&h;
}
__device__ __forceinline__ float bf2f(unsigned u16) {
    return __uint_as_float(u16 << 16);
}

// unpack a packed bf16 pair (one u32) into an f32 pair: 2 VALU ops
__device__ __forceinline__ f32x2 bfpair(unsigned u) {
    union { unsigned i[2]; f32x2 f; } t;
    t.i[0] = u << 16;            // lo bf16 -> f32 bits
    t.i[1] = u & 0xffff0000u;    // hi bf16 -> f32 bits
    return t.f;
}
// acc = x*w + acc, packed (VOP3P). Deterministic packed issue via inline asm.
__device__ __forceinline__ void pkfma(f32x2& acc, f32x2 x, f32x2 w) {
    asm("v_pk_fma_f32 %0, %1, %2, %0" : "+v"(acc) : "v"(x), "v"(w));
}

// ---------------- W prep (bf16 col-major) + ctrl zero + out zero ----------------
__global__ void k_wprep(const float* __restrict__ W1, const float* __restrict__ W2,
                        const float* __restrict__ W3, unsigned short* __restrict__ WT1,
                        unsigned short* __restrict__ WT2, unsigned short* __restrict__ WT3,
                        int* __restrict__ ctrl, float* __restrict__ outz) {
    int i = blockIdx.x * blockDim.x + threadIdx.x;
    if (i < NCTRL) ctrl[i] = 0;                  // incl. wc[4] work counters
    if (i < GG * 64) outz[i] = 0.f;              // pool accumulators
    if (i < 128 * 128) {
        int k = i >> 7, n = i & 127;
        WT1[n * 128 + k] = f2bf(W1[i]);
        WT2[n * 128 + k] = f2bf(W2[i]);
    }
    if (i < 128 * 64) {
        int k = i >> 6, n = i & 63;
        WT3[n * 128 + k] = f2bf(W3[i]);
    }
}

// ---------------- FUSED: binA (edge binning) || gemm1 (x @ W1) -------------------
constexpr int GEMM_BLKS = (NN + 63) / 64;        // 782

__global__ __launch_bounds__(256) void k_binA_gemm1(
        const int* __restrict__ src, const int* __restrict__ dst,
        int* __restrict__ cursor, unsigned* __restrict__ ebuf,
        const float* __restrict__ x, const unsigned short* __restrict__ WT,
        unsigned short* __restrict__ out16) {
    int tid = threadIdx.x;
    if (blockIdx.x < NBLK_A) {
        // ---------------- binA body (R11-proven) ----------------
        __shared__ int hist[512];
        __shared__ int lstart[512];
        __shared__ int gbase[NBUCK];
        __shared__ int lcur[NBUCK];
        __shared__ unsigned stage[EPB];

        int e0 = blockIdx.x * EPB;
        int nloc = min(EPB, NE - e0);

        hist[tid] = 0;
        hist[tid + 256] = 0;
        __syncthreads();
        for (int k = 0; k < EPB / 256; ++k) {
            int e = e0 + k * 256 + tid;
            if (e < NE) atomicAdd(&hist[dst[e] >> 7], 1);
        }
        __syncthreads();

        int v0 = hist[tid];
        lstart[tid] = v0;
        __syncthreads();
        for (int off = 1; off < 256; off <<= 1) {
            int t = (tid >= off) ? lstart[tid - off] : 0;
            __syncthreads();
            lstart[tid] += t;
            __syncthreads();
        }
        int v1 = hist[256 + tid];
        lstart[256 + tid] = v1;
        __syncthreads();
        for (int off = 1; off < 256; off <<= 1) {
            int t = (tid >= off) ? lstart[256 + tid - off] : 0;
            __syncthreads();
            lstart[256 + tid] += t;
            __syncthreads();
        }
        int lowTotal = lstart[255];
        int ex0 = lstart[tid] - v0;
        int ex1 = lstart[256 + tid] - v1 + lowTotal;
        __syncthreads();
        lstart[tid] = ex0;
        lstart[256 + tid] = ex1;
        __syncthreads();

        for (int i = tid; i < NBUCK; i += 256) {
            int h = hist[i];
            gbase[i] = (h > 0) ? atomicAdd(&cursor[i], h) : 0;
            lcur[i] = lstart[i];
        }
        __syncthreads();

        for (int k = 0; k < EPB / 256; ++k) {
            int e = e0 + k * 256 + tid;
            if (e < NE) {
                int d = dst[e];
                int pos = atomicAdd(&lcur[d >> 7], 1);
                stage[pos] = (unsigned)src[e] | ((unsigned)d << 16);
            }
        }
        __syncthreads();

        for (int i = tid; i < nloc; i += 256) {
            unsigned rec = stage[i];
            int bk = rec >> 23;
            int gpos = gbase[bk] + (i - lstart[bk]);
            if (gpos < BCAP) ebuf[(size_t)bk * BCAP + gpos] = rec;
        }
    } else {
        // ---------------- gemm1 body (R12-proven, A = fp32 x) ----------------
        int bid = blockIdx.x - NBLK_A;
        int wave = tid >> 6, lane = tid & 63;
        int row0 = bid * 64 + wave * 16;
        if (row0 >= NN) return;
        int lrow = lane & 15;
        int lk8 = lane >> 4;
        int row = row0 + lrow;

        shortx8 afrag[4];
#pragma unroll
        for (int ks = 0; ks < 4; ++ks) {
            int k0 = ks * 32 + lk8 * 8;
            float4 f0 = *(const float4*)&x[(size_t)row * 128 + k0];
            float4 f1 = *(const float4*)&x[(size_t)row * 128 + k0 + 4];
            union { shortx8 v; unsigned short u[8]; } t;
            t.u[0] = f2bf(f0.x); t.u[1] = f2bf(f0.y);
            t.u[2] = f2bf(f0.z); t.u[3] = f2bf(f0.w);
            t.u[4] = f2bf(f1.x); t.u[5] = f2bf(f1.y);
            t.u[6] = f2bf(f1.z); t.u[7] = f2bf(f1.w);
            afrag[ks] = t.v;
        }

        f32x4 acc[8];
#pragma unroll
        for (int t = 0; t < 8; ++t) acc[t] = {0.f, 0.f, 0.f, 0.f};
#pragma unroll
        for (int t = 0; t < 8; ++t) {
#pragma unroll
            for (int ks = 0; ks < 4; ++ks) {
                shortx8 b = *(const shortx8*)&WT[(size_t)(t * 16 + lrow) * 128 + ks * 32 + lk8 * 8];
                acc[t] = __builtin_amdgcn_mfma_f32_16x16x32_bf16(afrag[ks], b, acc[t], 0, 0, 0);
            }
        }
#pragma unroll
        for (int t = 0; t < 8; ++t) {
#pragma unroll
            for (int r = 0; r < 4; ++r) {
                int orow = row0 + lk8 * 4 + r;
                out16[(size_t)orow * 128 + t * 16 + lrow] = f2bf(acc[t][r]);
            }
        }
    }
}

// ---------------- build phase B: DIRECT-WRITE CSR (R24-proven) -------------------
__global__ __launch_bounds__(256) void k_binB(const int* __restrict__ cursor,
                                              const unsigned* __restrict__ ebuf,
                                              int* __restrict__ cnt,
                                              int* __restrict__ csr_idx,
                                              float* __restrict__ dinv,
                                              const int* __restrict__ batch,
                                              int* __restrict__ gstart,
                                              int* __restrict__ gend) {
    __shared__ int ncnt[128];

    int bk = blockIdx.x;
    int tid = threadIdx.x;
    int n0 = bk << 7;
    int count = min(cursor[bk], BCAP);

    if (tid < 128) ncnt[tid] = 0;
    __syncthreads();
    for (int i = tid; i < count; i += 256) {
        unsigned rec = ebuf[(size_t)bk * BCAP + i];
        int nl = (rec >> 16) & 127;
        int p = atomicAdd(&ncnt[nl], 1);
        if (p < SLOT)
            csr_idx[(size_t)(n0 + nl) * SLOT + p] = (int)(rec & 0xFFFFu);
    }
    __syncthreads();
    if (tid < 128) {
        int node = n0 + tid;
        if (node < NN) {
            int c = ncnt[tid];
            cnt[node] = c;
            dinv[node] = rsqrtf((float)c + 1.0f);   // +1 self loop
            int b = batch[node];
            if (node == 0 || batch[node - 1] != b) gstart[b] = node;
            if (node == NN - 1 || batch[node + 1] != b) gend[b] = node + 1;
        }
    }
}

// ---------------- device body: agg(128ch,+bias,relu) -> @WT -> out16 (R18) -------
template <int DO>
__device__ __forceinline__ void agg_gemm_body(
        int nb0, const unsigned short* __restrict__ h16,
        const int* __restrict__ cnt, const int* __restrict__ csr_idx,
        const float* __restrict__ dinv, const float* __restrict__ bias,
        const unsigned short* __restrict__ WT,
        unsigned short* __restrict__ out16,
        unsigned short* A) {
    int tid = threadIdx.x;
    int wave = tid >> 6, lane = tid & 63;
    int quad = lane >> 4;
    int l16 = lane & 15;
    const uint4* h4 = (const uint4*)h16;

    // ---- phase 1: each wave aggregates 4 nodes ----
    for (int q = 0; q < 4; ++q) {
        int wid = nb0 + wave * 4 + q;        // always < NN
        int n = min(cnt[wid], SLOT);         // wave-uniform
        float dv = dinv[wid];

        int rec = 0; float wl = 0.f;
        if (lane < n) {
            rec = csr_idx[wid * SLOT + lane];   // coalesced 256 B
            wl = dv * dinv[rec];
        }

        f32x2 c0 = {0.f, 0.f}, c1 = {0.f, 0.f}, c2 = {0.f, 0.f}, c3 = {0.f, 0.f};
        int jb_end = (n + 15) & ~15;         // wave-uniform -> EXEC-safe shfl
        for (int jb = 0; jb < jb_end; jb += 16) {
            int j0 = jb + quad;
            int s0 = __shfl(rec, j0);
            int s1 = __shfl(rec, j0 + 4);
            int s2 = __shfl(rec, j0 + 8);
            int s3 = __shfl(rec, j0 + 12);
            float w0 = __shfl(wl, j0);
            float w1 = __shfl(wl, j0 + 4);
            float w2 = __shfl(wl, j0 + 8);
            float w3 = __shfl(wl, j0 + 12);
            uint4 v0 = h4[(size_t)s0 * 16 + l16];
            uint4 v1 = h4[(size_t)s1 * 16 + l16];
            uint4 v2 = h4[(size_t)s2 * 16 + l16];
            uint4 v3 = h4[(size_t)s3 * 16 + l16];
            f32x2 w0v = {w0, w0}, w1v = {w1, w1}, w2v = {w2, w2}, w3v = {w3, w3};
            pkfma(c0, bfpair(v0.x), w0v); pkfma(c1, bfpair(v0.y), w0v);
            pkfma(c2, bfpair(v0.z), w0v); pkfma(c3, bfpair(v0.w), w0v);
            pkfma(c0, bfpair(v1.x), w1v); pkfma(c1, bfpair(v1.y), w1v);
            pkfma(c2, bfpair(v1.z), w1v); pkfma(c3, bfpair(v1.w), w1v);
            pkfma(c0, bfpair(v2.x), w2v); pkfma(c1, bfpair(v2.y), w2v);
            pkfma(c2, bfpair(v2.z), w2v); pkfma(c3, bfpair(v2.w), w2v);
            pkfma(c0, bfpair(v3.x), w3v); pkfma(c1, bfpair(v3.y), w3v);
            pkfma(c2, bfpair(v3.z), w3v); pkfma(c3, bfpair(v3.w), w3v);
        }

        c0.x += __shfl_down(c0.x, 32); c0.y += __shfl_down(c0.y, 32);
        c1.x += __shfl_down(c1.x, 32); c1.y += __shfl_down(c1.y, 32);
        c2.x += __shfl_down(c2.x, 32); c2.y += __shfl_down(c2.y, 32);
        c3.x += __shfl_down(c3.x, 32); c3.y += __shfl_down(c3.y, 32);
        c0.x += __shfl_down(c0.x, 16); c0.y += __shfl_down(c0.y, 16);
        c1.x += __shfl_down(c1.x, 16); c1.y += __shfl_down(c1.y, 16);
        c2.x += __shfl_down(c2.x, 16); c2.y += __shfl_down(c2.y, 16);
        c3.x += __shfl_down(c3.x, 16); c3.y += __shfl_down(c3.y, 16);
        if (lane < 16) {
            float d2 = dv * dv;
            uint4 hv = h4[(size_t)wid * 16 + l16];
            float4 b0 = *(const float4*)&bias[l16 * 8];
            float4 b1 = *(const float4*)&bias[l16 * 8 + 4];
            f32x2 d2v = {d2, d2};
            pkfma(c0, bfpair(hv.x), d2v);
            pkfma(c1, bfpair(hv.y), d2v);
            pkfma(c2, bfpair(hv.z), d2v);
            pkfma(c3, bfpair(hv.w), d2v);
            float a0 = fmaxf(c0.x + b0.x, 0.f), a1 = fmaxf(c0.y + b0.y, 0.f);
            float a2 = fmaxf(c1.x + b0.z, 0.f), a3 = fmaxf(c1.y + b0.w, 0.f);
            float a4 = fmaxf(c2.x + b1.x, 0.f), a5 = fmaxf(c2.y + b1.y, 0.f);
            float a6 = fmaxf(c3.x + b1.z, 0.f), a7 = fmaxf(c3.y + b1.w, 0.f);
            union { uint4 v; unsigned short u[8]; } o;
            o.u[0] = f2bf(a0); o.u[1] = f2bf(a1); o.u[2] = f2bf(a2); o.u[3] = f2bf(a3);
            o.u[4] = f2bf(a4); o.u[5] = f2bf(a5); o.u[6] = f2bf(a6); o.u[7] = f2bf(a7);
            int row = wave * 4 + q;
            int col16 = l16 ^ (row & 7);          // 16B-granule XOR swizzle (G4)
            *(uint4*)&A[row * 128 + col16 * 8] = o.v;
        }
    }
    __syncthreads();

    // ---- phase 2: 16x128 (LDS) @ 128xDO (WT) -> 16xDO tile ----
    int lrow = lane & 15;
    int lk8 = lane >> 4;
    shortx8 af[4];
#pragma unroll
    for (int ks = 0; ks < 4; ++ks) {
        int col16 = (ks * 4 + lk8) ^ (lrow & 7);  // same swizzle on read
        af[ks] = *(const shortx8*)&A[lrow * 128 + col16 * 8];
    }
    constexpr int NT = DO / 16;                   // 8 (DO=128) or 4 (DO=64)
    constexpr int TPW = (NT + 3) / 4;             // tiles per wave: 2 or 1
#pragma unroll
    for (int tt = 0; tt < TPW; ++tt) {
        int t = wave + tt * 4;
        f32x4 acc = {0.f, 0.f, 0.f, 0.f};
#pragma unroll
        for (int ks = 0; ks < 4; ++ks) {
            shortx8 b = *(const shortx8*)&WT[(size_t)(t * 16 + lrow) * 128 + ks * 32 + lk8 * 8];
            acc = __builtin_amdgcn_mfma_f32_16x16x32_bf16(af[ks], b, acc, 0, 0, 0);
        }
#pragma unroll
        for (int r = 0; r < 4; ++r) {
            int orow = nb0 + lk8 * 4 + r;
            out16[(size_t)orow * DO + t * 16 + lrow] = f2bf(acc[r]);
        }
    }
}

// ---------------- device body: agg DO=64 (+b3) -> pool partial atomics (R25) -----
__device__ __forceinline__ void aggpool_body(
        int nb0, const unsigned short* __restrict__ h16,
        const int* __restrict__ cnt, const int* __restrict__ csr_idx,
        const float* __restrict__ dinv, const float* __restrict__ b,
        const int* __restrict__ batch, const int* __restrict__ gstart,
        const int* __restrict__ gend, float* __restrict__ out,
        float (*sm)[64]) {
    int tid = threadIdx.x;
    int wave = tid >> 6, lane = tid & 63;
    int wid = nb0 + wave;
    int oct = lane >> 3;             // 8 edge streams
    int l8 = lane & 7;               // 8 lanes x 8 bf16 ch = 64 ch
    int n = min(cnt[wid], SLOT);
    float dv = dinv[wid];

    int rec = 0; float wl = 0.f;
    if (lane < n) {
        rec = csr_idx[wid * SLOT + lane];
        wl = dv * dinv[rec];
    }

    const uint4* h4 = (const uint4*)h16;
    f32x2 c0 = {0.f, 0.f}, c1 = {0.f, 0.f}, c2 = {0.f, 0.f}, c3 = {0.f, 0.f};

    int jb_end = (n + 15) & ~15;
    for (int jb = 0; jb < jb_end; jb += 16) {
        int j0 = jb + oct;           // j0, j0+8 both < jb_end <= 64
        int s0 = __shfl(rec, j0);
        int s1 = __shfl(rec, j0 + 8);
        float w0 = __shfl(wl, j0);
        float w1 = __shfl(wl, j0 + 8);
        uint4 v0 = h4[(size_t)s0 * 8 + l8];
        uint4 v1 = h4[(size_t)s1 * 8 + l8];
        f32x2 w0v = {w0, w0}, w1v = {w1, w1};
        pkfma(c0, bfpair(v0.x), w0v); pkfma(c1, bfpair(v0.y), w0v);
        pkfma(c2, bfpair(v0.z), w0v); pkfma(c3, bfpair(v0.w), w0v);
        pkfma(c0, bfpair(v1.x), w1v); pkfma(c1, bfpair(v1.y), w1v);
        pkfma(c2, bfpair(v1.z), w1v); pkfma(c3, bfpair(v1.w), w1v);
    }

    c0.x += __shfl_down(c0.x, 32); c0.y += __shfl_down(c0.y, 32);
    c1.x += __shfl_down(c1.x, 32); c1.y += __shfl_down(c1.y, 32);
    c2.x += __shfl_down(c2.x, 32); c2.y += __shfl_down(c2.y, 32);
    c3.x += __shfl_down(c3.x, 32); c3.y += __shfl_down(c3.y, 32);
    c0.x += __shfl_down(c0.x, 16); c0.y += __shfl_down(c0.y, 16);
    c1.x += __shfl_down(c1.x, 16); c1.y += __shfl_down(c1.y, 16);
    c2.x += __shfl_down(c2.x, 16); c2.y += __shfl_down(c2.y, 16);
    c3.x += __shfl_down(c3.x, 16); c3.y += __shfl_down(c3.y, 16);
    c0.x += __shfl_down(c0.x, 8);  c0.y += __shfl_down(c0.y, 8);
    c1.x += __shfl_down(c1.x, 8);  c1.y += __shfl_down(c1.y, 8);
    c2.x += __shfl_down(c2.x, 8);  c2.y += __shfl_down(c2.y, 8);
    c3.x += __shfl_down(c3.x, 8);  c3.y += __shfl_down(c3.y, 8);
    if (lane < 8) {
        float d2 = dv * dv;
        uint4 hv = h4[(size_t)wid * 8 + l8];
        float4 b0 = *(const float4*)&b[l8 * 8];
        float4 b1 = *(const float4*)&b[l8 * 8 + 4];
        f32x2 d2v = {d2, d2};
        pkfma(c0, bfpair(hv.x), d2v);
        pkfma(c1, bfpair(hv.y), d2v);
        pkfma(c2, bfpair(hv.z), d2v);
        pkfma(c3, bfpair(hv.w), d2v);
        sm[wave][l8 * 8 + 0] = c0.x + b0.x;
        sm[wave][l8 * 8 + 1] = c0.y + b0.y;
        sm[wave][l8 * 8 + 2] = c1.x + b0.z;
        sm[wave][l8 * 8 + 3] = c1.y + b0.w;
        sm[wave][l8 * 8 + 4] = c2.x + b1.x;
        sm[wave][l8 * 8 + 5] = c2.y + b1.y;
        sm[wave][l8 * 8 + 6] = c3.x + b1.z;
        sm[wave][l8 * 8 + 7] = c3.y + b1.w;
    }
    __syncthreads();

    if (tid < 64) {
        int ch = tid;
        int cur = batch[nb0];
        float acc = 0.f;
#pragma unroll
        for (int w = 0; w < 4; ++w) {
            int g = batch[nb0 + w];
            if (g != cur) {
                float inv = 1.0f / fmaxf((float)(gend[cur] - gstart[cur]), 1.0f);
                atomicAdd(&out[(size_t)cur * 64 + ch], acc * inv);
                acc = 0.f;
                cur = g;
            }
            acc += sm[w][ch];
        }
        float inv = 1.0f / fmaxf((float)(gend[cur] - gstart[cur]), 1.0f);
        atomicAdd(&out[(size_t)cur * 64 + ch], acc * inv);
    }
}

// ---------------- cooperative tail: agg1@W2 -> agg2@W3 -> agg3+pool --------------
__global__ __launch_bounds__(256) void k_tail(
        unsigned short* bufA16, unsigned short* bufC16,
        const int* cnt, const int* csr_idx, const float* dinv,
        const float* b1, const float* b2, const float* b3,
        const unsigned short* WT2, const unsigned short* WT3,
        const int* batch, const int* gstart, const int* gend,
        float* out, int* wc) {
    __shared__ unsigned short A[16 * 128];   // agg_gemm tile
    __shared__ float sm[4][64];              // pool partials
    __shared__ int s_u;
    cg::grid_group grid = cg::this_grid();
    int tid = threadIdx.x;

    // ---- phase 0: agg1(+b1,relu) @ W2 -> bufC16 (3125 units of 16 nodes) ----
    for (;;) {
        if (tid == 0) s_u = atomicAdd(&wc[0], 1);
        __syncthreads();
        int u = s_u;
        if (u >= NN / 16) break;             // uniform break
        agg_gemm_body<128>(u * 16, bufA16, cnt, csr_idx, dinv, b1, WT2, bufC16, A);
        __syncthreads();                     // LDS A + s_u reuse guard
    }
    __threadfence();                         // device-scope release (G16)
    grid.sync();

    // ---- phase 1: agg2(+b2,relu) @ W3 -> bufA16 ----
    for (;;) {
        if (tid == 0) s_u = atomicAdd(&wc[1], 1);
        __syncthreads();
        int u = s_u;
        if (u >= NN / 16) break;
        agg_gemm_body<64>(u * 16, bufC16, cnt, csr_idx, dinv, b2, WT3, bufA16, A);
        __syncthreads();
    }
    __threadfence();
    grid.sync();

    // ---- phase 2: agg3(+b3) -> pool partial atomics (12500 units of 4 nodes) ----
    for (;;) {
        if (tid == 0) s_u = atomicAdd(&wc[2], 1);
        __syncthreads();
        int u = s_u;
        if (u >= NN / 4) break;
        aggpool_body(u * 4, bufA16, cnt, csr_idx, dinv, b3, batch, gstart, gend,
                     out, sm);
        __syncthreads();
    }
}

extern "C" void kernel_launch(void* const* d_in, const int* in_sizes, int n_in,
                              void* d_out, int out_size, void* d_ws, size_t ws_size,
                              hipStream_t stream) {
    const float* x     = (const float*)d_in[0];
    const int*   ei    = (const int*)d_in[1];
    const int*   batch = (const int*)d_in[2];
    const float* W1 = (const float*)d_in[3];
    const float* b1 = (const float*)d_in[4];
    const float* W2 = (const float*)d_in[5];
    const float* b2 = (const float*)d_in[6];
    const float* W3 = (const float*)d_in[7];
    const float* b3 = (const float*)d_in[8];
    float* out = (float*)d_out;

    const int* src = ei;
    const int* dst = ei + NE;

    char* p = (char*)d_ws;
    auto alloc = [&](size_t nbytes) -> void* {
        void* r = (void*)p;
        p += (nbytes + 255) & ~((size_t)255);
        return r;
    };
    // total ~51.9 MB (within proven envelope)
    int*   ctrl    = (int*)alloc((size_t)NCTRL * 4);
    int*   cursor  = ctrl;
    int*   gstart  = ctrl + NBUCK;
    int*   gend    = ctrl + NBUCK + GG;
    int*   wc      = ctrl + NBUCK + 2 * GG;           // 4 work counters
    int*   cnt     = (int*)alloc((size_t)NN * 4);
    float* dinv    = (float*)alloc((size_t)NN * 4);
    int*   csr_idx = (int*)alloc((size_t)NN * SLOT * 4);
    unsigned short* bufA16 = (unsigned short*)alloc((size_t)NN * 128 * 2);   // gemm1/gemm3 out
    float* bufB    = (float*)alloc((size_t)NN * 128 * 4);                    // staging
    unsigned short* WT1 = (unsigned short*)alloc(128 * 128 * 2);
    unsigned short* WT2 = (unsigned short*)alloc(128 * 128 * 2);
    unsigned short* WT3 = (unsigned short*)alloc(128 * 64 * 2);
    // aliases on bufB (stream order makes these safe):
    unsigned* ebuf = (unsigned*)bufB;                 // build staging, dead after binB
    unsigned short* bufC16 = (unsigned short*)bufB;   // gemm2 out (tail phase 0/1)

    // --- prep: weights (bf16 col-major) + ctrl/wc zero + out zero ---
    k_wprep<<<128, 256, 0, stream>>>(W1, W2, W3, WT1, WT2, WT3, ctrl, out);

    // --- binA (edge binning) || gemm1 (x @ W1), overlapped ---
    k_binA_gemm1<<<NBLK_A + GEMM_BLKS, 256, 0, stream>>>(src, dst, cursor, ebuf,
                                                         x, WT1, bufA16);

    // --- build phase B (direct-write CSR) ---
    k_binB<<<NBUCK, 256, 0, stream>>>(cursor, ebuf, cnt, csr_idx, dinv, batch,
                                      gstart, gend);

    // --- cooperative tail: agg1@W2 -> agg2@W3 -> agg3+pool (2 grid.syncs) ---
    int bpc = 0;
    hipOccupancyMaxActiveBlocksPerMultiprocessor(&bpc, k_tail, 256, 0);
    if (bpc < 1) bpc = 1;
    if (bpc > 8) bpc = 8;                     // 8 blocks/CU = 32 waves/CU cap
    dim3 tgrid(bpc * 256, 1, 1);              // 256 CUs on MI355X
    void* args[] = {(void*)&bufA16, (void*)&bufC16, (void*)&cnt, (void*)&csr_idx,
                    (void*)&dinv, (void*)&b1, (void*)&b2, (void*)&b3,
                    (void*)&WT2, (void*)&WT3, (void*)&batch, (void*)&gstart,
                    (void*)&gend, (void*)&out, (void*)&wc};
    hipLaunchCooperativeKernel(k_tail, tgrid, dim3(256, 1, 1), args, 0, stream);
}

// Round 13
// 231.957 us; speedup vs baseline: 2.9006x; 2.9006x over previous
//
#include <hip/hip_runtime.h>
#include <hip/hip_bf16.h>

// ---------------------------------------------------------------------------
// 3-layer GCN + global mean pool, MI355X — round 27: revert to R25 (best, 232.9us)
//
// R26 post-mortem: cooperative tail = 753us vs ~125us of contained work.
// FETCH/WRITE matched the sum of phases (memory work unchanged) but HBM ran
// at 300GB/s, VALU 5.6% — pure serialization: ~25K same-address device-scope
// atomics on the work counters (cross-XCD serialized), 2 extra barriers/unit,
// and grid-wide straggler waits at grid.sync. Third "cheap-looking
// serialization" trap (after R16 scatter, R20 hot atomics). Reverting to the
// proven R25 structure:
//   wprep -> binA||gemm1 -> binB(direct CSR) -> agg1@W2 -> agg2@W3 -> agg3+pool
// Aggs are pinned at the compulsory cross-XCD FETCH floor (83MB = 8 XCDs x
// ~11MB compulsory random-gather set; analytic match). Remaining levers all
// refuted by measurement: SWP (R17), MLP depth (R19), NT (R23), atomic pool
// (R20), cooperative sync (R26).
// ---------------------------------------------------------------------------

constexpr int NN   = 50000;   // nodes (divisible by 16)
constexpr int NE   = 800000;  // edges
constexpr int GG   = 512;     // graphs
constexpr int SLOT = 64;      // padded slots/node

constexpr int NBUCK  = (NN + 127) / 128;       // 391 buckets of 128 nodes
constexpr int BCAP   = 2560;                   // per-bucket capacity
constexpr int EPB    = 2048;                   // edges per binA block
constexpr int NBLK_A = (NE + EPB - 1) / EPB;   // 391 blocks
constexpr int NCTRL  = NBUCK + 2 * GG;         // cursor + gstart + gend words

using shortx8 = __attribute__((ext_vector_type(8))) short;   // 8 bf16 = 4 VGPRs
using f32x4   = __attribute__((ext_vector_type(4))) float;
using f32x2   = __attribute__((ext_vector_type(2))) float;

__device__ __forceinline__ unsigned short f2bf(float f) {
    __hip_bfloat16 h = __float2bfloat16(f);   // RNE
    return *(unsigned short*)&h;
}
__device__ __forceinline__ float bf2f(unsigned u16) {
    return __uint_as_float(u16 << 16);
}

// unpack a packed bf16 pair (one u32) into an f32 pair: 2 VALU ops
__device__ __forceinline__ f32x2 bfpair(unsigned u) {
    union { unsigned i[2]; f32x2 f; } t;
    t.i[0] = u << 16;            // lo bf16 -> f32 bits
    t.i[1] = u & 0xffff0000u;    // hi bf16 -> f32 bits
    return t.f;
}
// acc = x*w + acc, packed (VOP3P). Deterministic packed issue via inline asm.
__device__ __forceinline__ void pkfma(f32x2& acc, f32x2 x, f32x2 w) {
    asm("v_pk_fma_f32 %0, %1, %2, %0" : "+v"(acc) : "v"(x), "v"(w));
}

// ---------------- W prep (bf16 col-major) + ctrl zero + out zero ----------------
__global__ void k_wprep(const float* __restrict__ W1, const float* __restrict__ W2,
                        const float* __restrict__ W3, unsigned short* __restrict__ WT1,
                        unsigned short* __restrict__ WT2, unsigned short* __restrict__ WT3,
                        int* __restrict__ ctrl, float* __restrict__ outz) {
    int i = blockIdx.x * blockDim.x + threadIdx.x;
    if (i < NCTRL) ctrl[i] = 0;
    if (i < GG * 64) outz[i] = 0.f;              // pool accumulators
    if (i < 128 * 128) {
        int k = i >> 7, n = i & 127;
        WT1[n * 128 + k] = f2bf(W1[i]);
        WT2[n * 128 + k] = f2bf(W2[i]);
    }
    if (i < 128 * 64) {
        int k = i >> 6, n = i & 63;
        WT3[n * 128 + k] = f2bf(W3[i]);
    }
}

// ---------------- FUSED: binA (edge binning) || gemm1 (x @ W1) -------------------
// Independent work overlapped in one kernel: blocks [0, NBLK_A) run binA,
// blocks [NBLK_A, NBLK_A + GEMM_BLKS) run gemm1 (A = fp32 x).
constexpr int GEMM_BLKS = (NN + 63) / 64;        // 782

__global__ __launch_bounds__(256) void k_binA_gemm1(
        const int* __restrict__ src, const int* __restrict__ dst,
        int* __restrict__ cursor, unsigned* __restrict__ ebuf,
        const float* __restrict__ x, const unsigned short* __restrict__ WT,
        unsigned short* __restrict__ out16) {
    int tid = threadIdx.x;
    if (blockIdx.x < NBLK_A) {
        // ---------------- binA body (R11-proven) ----------------
        __shared__ int hist[512];
        __shared__ int lstart[512];
        __shared__ int gbase[NBUCK];
        __shared__ int lcur[NBUCK];
        __shared__ unsigned stage[EPB];

        int e0 = blockIdx.x * EPB;
        int nloc = min(EPB, NE - e0);

        hist[tid] = 0;
        hist[tid + 256] = 0;
        __syncthreads();
        for (int k = 0; k < EPB / 256; ++k) {
            int e = e0 + k * 256 + tid;
            if (e < NE) atomicAdd(&hist[dst[e] >> 7], 1);
        }
        __syncthreads();

        int v0 = hist[tid];
        lstart[tid] = v0;
        __syncthreads();
        for (int off = 1; off < 256; off <<= 1) {
            int t = (tid >= off) ? lstart[tid - off] : 0;
            __syncthreads();
            lstart[tid] += t;
            __syncthreads();
        }
        int v1 = hist[256 + tid];
        lstart[256 + tid] = v1;
        __syncthreads();
        for (int off = 1; off < 256; off <<= 1) {
            int t = (tid >= off) ? lstart[256 + tid - off] : 0;
            __syncthreads();
            lstart[256 + tid] += t;
            __syncthreads();
        }
        int lowTotal = lstart[255];
        int ex0 = lstart[tid] - v0;
        int ex1 = lstart[256 + tid] - v1 + lowTotal;
        __syncthreads();
        lstart[tid] = ex0;
        lstart[256 + tid] = ex1;
        __syncthreads();

        for (int i = tid; i < NBUCK; i += 256) {
            int h = hist[i];
            gbase[i] = (h > 0) ? atomicAdd(&cursor[i], h) : 0;
            lcur[i] = lstart[i];
        }
        __syncthreads();

        for (int k = 0; k < EPB / 256; ++k) {
            int e = e0 + k * 256 + tid;
            if (e < NE) {
                int d = dst[e];
                int pos = atomicAdd(&lcur[d >> 7], 1);
                stage[pos] = (unsigned)src[e] | ((unsigned)d << 16);
            }
        }
        __syncthreads();

        for (int i = tid; i < nloc; i += 256) {
            unsigned rec = stage[i];
            int bk = rec >> 23;
            int gpos = gbase[bk] + (i - lstart[bk]);
            if (gpos < BCAP) ebuf[(size_t)bk * BCAP + gpos] = rec;
        }
    } else {
        // ---------------- gemm1 body (R12-proven, A = fp32 x) ----------------
        int bid = blockIdx.x - NBLK_A;
        int wave = tid >> 6, lane = tid & 63;
        int row0 = bid * 64 + wave * 16;
        if (row0 >= NN) return;
        int lrow = lane & 15;
        int lk8 = lane >> 4;
        int row = row0 + lrow;

        shortx8 afrag[4];
#pragma unroll
        for (int ks = 0; ks < 4; ++ks) {
            int k0 = ks * 32 + lk8 * 8;
            float4 f0 = *(const float4*)&x[(size_t)row * 128 + k0];
            float4 f1 = *(const float4*)&x[(size_t)row * 128 + k0 + 4];
            union { shortx8 v; unsigned short u[8]; } t;
            t.u[0] = f2bf(f0.x); t.u[1] = f2bf(f0.y);
            t.u[2] = f2bf(f0.z); t.u[3] = f2bf(f0.w);
            t.u[4] = f2bf(f1.x); t.u[5] = f2bf(f1.y);
            t.u[6] = f2bf(f1.z); t.u[7] = f2bf(f1.w);
            afrag[ks] = t.v;
        }

        f32x4 acc[8];
#pragma unroll
        for (int t = 0; t < 8; ++t) acc[t] = {0.f, 0.f, 0.f, 0.f};
#pragma unroll
        for (int t = 0; t < 8; ++t) {
#pragma unroll
            for (int ks = 0; ks < 4; ++ks) {
                shortx8 b = *(const shortx8*)&WT[(size_t)(t * 16 + lrow) * 128 + ks * 32 + lk8 * 8];
                acc[t] = __builtin_amdgcn_mfma_f32_16x16x32_bf16(afrag[ks], b, acc[t], 0, 0, 0);
            }
        }
#pragma unroll
        for (int t = 0; t < 8; ++t) {
#pragma unroll
            for (int r = 0; r < 4; ++r) {
                int orow = row0 + lk8 * 4 + r;
                out16[(size_t)orow * 128 + t * 16 + lrow] = f2bf(acc[t][r]);
            }
        }
    }
}

// ---------------- build phase B: DIRECT-WRITE CSR (R24-proven) -------------------
__global__ __launch_bounds__(256) void k_binB(const int* __restrict__ cursor,
                                              const unsigned* __restrict__ ebuf,
                                              int* __restrict__ cnt,
                                              int* __restrict__ csr_idx,
                                              float* __restrict__ dinv,
                                              const int* __restrict__ batch,
                                              int* __restrict__ gstart,
                                              int* __restrict__ gend) {
    __shared__ int ncnt[128];

    int bk = blockIdx.x;
    int tid = threadIdx.x;
    int n0 = bk << 7;
    int count = min(cursor[bk], BCAP);

    if (tid < 128) ncnt[tid] = 0;
    __syncthreads();
    for (int i = tid; i < count; i += 256) {
        unsigned rec = ebuf[(size_t)bk * BCAP + i];
        int nl = (rec >> 16) & 127;
        int p = atomicAdd(&ncnt[nl], 1);
        if (p < SLOT)
            csr_idx[(size_t)(n0 + nl) * SLOT + p] = (int)(rec & 0xFFFFu);
    }
    __syncthreads();
    if (tid < 128) {
        int node = n0 + tid;
        if (node < NN) {
            int c = ncnt[tid];
            cnt[node] = c;
            dinv[node] = rsqrtf((float)c + 1.0f);   // +1 self loop
            int b = batch[node];
            if (node == 0 || batch[node - 1] != b) gstart[b] = node;
            if (node == NN - 1 || batch[node + 1] != b) gend[b] = node + 1;
        }
    }
}

// ---------------- FUSED: agg(128ch, +bias, relu) -> @W_next -> out16[NN,DO] -----
// R18-proven body (single gather stream/node; 4 nodes/wave sequential).
template <int DO>
__global__ __launch_bounds__(256) void k_agg_gemm(
        const unsigned short* __restrict__ h16,   // gather source [NN][128] bf16
        const int* __restrict__ cnt, const int* __restrict__ csr_idx,
        const float* __restrict__ dinv, const float* __restrict__ bias,
        const unsigned short* __restrict__ WT,    // [DO][128] bf16 col-major
        unsigned short* __restrict__ out16) {     // [NN][DO] bf16
    __shared__ unsigned short A[16 * 128];        // 4 KB, 16B-granule swizzled

    int tid = threadIdx.x;
    int wave = tid >> 6, lane = tid & 63;
    int nb0 = blockIdx.x * 16;       // first node of this block (NN % 16 == 0)
    int quad = lane >> 4;            // 4 edge streams
    int l16 = lane & 15;             // 16 lanes x 8 bf16 ch = 128 ch
    const uint4* h4 = (const uint4*)h16;

    // ---- phase 1: each wave aggregates 4 nodes ----
    for (int q = 0; q < 4; ++q) {
        int wid = nb0 + wave * 4 + q;        // always < NN
        int n = min(cnt[wid], SLOT);         // wave-uniform
        float dv = dinv[wid];

        int rec = 0; float wl = 0.f;
        if (lane < n) {
            rec = csr_idx[wid * SLOT + lane];   // coalesced 256 B
            wl = dv * dinv[rec];
        }

        f32x2 c0 = {0.f, 0.f}, c1 = {0.f, 0.f}, c2 = {0.f, 0.f}, c3 = {0.f, 0.f};
        int jb_end = (n + 15) & ~15;         // wave-uniform -> EXEC-safe shfl
        for (int jb = 0; jb < jb_end; jb += 16) {
            int j0 = jb + quad;
            int s0 = __shfl(rec, j0);
            int s1 = __shfl(rec, j0 + 4);
            int s2 = __shfl(rec, j0 + 8);
            int s3 = __shfl(rec, j0 + 12);
            float w0 = __shfl(wl, j0);
            float w1 = __shfl(wl, j0 + 4);
            float w2 = __shfl(wl, j0 + 8);
            float w3 = __shfl(wl, j0 + 12);
            uint4 v0 = h4[(size_t)s0 * 16 + l16];
            uint4 v1 = h4[(size_t)s1 * 16 + l16];
            uint4 v2 = h4[(size_t)s2 * 16 + l16];
            uint4 v3 = h4[(size_t)s3 * 16 + l16];
            f32x2 w0v = {w0, w0}, w1v = {w1, w1}, w2v = {w2, w2}, w3v = {w3, w3};
            pkfma(c0, bfpair(v0.x), w0v); pkfma(c1, bfpair(v0.y), w0v);
            pkfma(c2, bfpair(v0.z), w0v); pkfma(c3, bfpair(v0.w), w0v);
            pkfma(c0, bfpair(v1.x), w1v); pkfma(c1, bfpair(v1.y), w1v);
            pkfma(c2, bfpair(v1.z), w1v); pkfma(c3, bfpair(v1.w), w1v);
            pkfma(c0, bfpair(v2.x), w2v); pkfma(c1, bfpair(v2.y), w2v);
            pkfma(c2, bfpair(v2.z), w2v); pkfma(c3, bfpair(v2.w), w2v);
            pkfma(c0, bfpair(v3.x), w3v); pkfma(c1, bfpair(v3.y), w3v);
            pkfma(c2, bfpair(v3.z), w3v); pkfma(c3, bfpair(v3.w), w3v);
        }

        c0.x += __shfl_down(c0.x, 32); c0.y += __shfl_down(c0.y, 32);
        c1.x += __shfl_down(c1.x, 32); c1.y += __shfl_down(c1.y, 32);
        c2.x += __shfl_down(c2.x, 32); c2.y += __shfl_down(c2.y, 32);
        c3.x += __shfl_down(c3.x, 32); c3.y += __shfl_down(c3.y, 32);
        c0.x += __shfl_down(c0.x, 16); c0.y += __shfl_down(c0.y, 16);
        c1.x += __shfl_down(c1.x, 16); c1.y += __shfl_down(c1.y, 16);
        c2.x += __shfl_down(c2.x, 16); c2.y += __shfl_down(c2.y, 16);
        c3.x += __shfl_down(c3.x, 16); c3.y += __shfl_down(c3.y, 16);
        if (lane < 16) {
            float d2 = dv * dv;
            uint4 hv = h4[(size_t)wid * 16 + l16];
            float4 b0 = *(const float4*)&bias[l16 * 8];
            float4 b1 = *(const float4*)&bias[l16 * 8 + 4];
            f32x2 d2v = {d2, d2};
            pkfma(c0, bfpair(hv.x), d2v);
            pkfma(c1, bfpair(hv.y), d2v);
            pkfma(c2, bfpair(hv.z), d2v);
            pkfma(c3, bfpair(hv.w), d2v);
            float a0 = fmaxf(c0.x + b0.x, 0.f), a1 = fmaxf(c0.y + b0.y, 0.f);
            float a2 = fmaxf(c1.x + b0.z, 0.f), a3 = fmaxf(c1.y + b0.w, 0.f);
            float a4 = fmaxf(c2.x + b1.x, 0.f), a5 = fmaxf(c2.y + b1.y, 0.f);
            float a6 = fmaxf(c3.x + b1.z, 0.f), a7 = fmaxf(c3.y + b1.w, 0.f);
            union { uint4 v; unsigned short u[8]; } o;
            o.u[0] = f2bf(a0); o.u[1] = f2bf(a1); o.u[2] = f2bf(a2); o.u[3] = f2bf(a3);
            o.u[4] = f2bf(a4); o.u[5] = f2bf(a5); o.u[6] = f2bf(a6); o.u[7] = f2bf(a7);
            int row = wave * 4 + q;
            int col16 = l16 ^ (row & 7);          // 16B-granule XOR swizzle (G4)
            *(uint4*)&A[row * 128 + col16 * 8] = o.v;
        }
    }
    __syncthreads();

    // ---- phase 2: 16x128 (LDS) @ 128xDO (WT) -> 16xDO tile ----
    int lrow = lane & 15;
    int lk8 = lane >> 4;
    shortx8 af[4];
#pragma unroll
    for (int ks = 0; ks < 4; ++ks) {
        int col16 = (ks * 4 + lk8) ^ (lrow & 7);  // same swizzle on read
        af[ks] = *(const shortx8*)&A[lrow * 128 + col16 * 8];
    }
    constexpr int NT = DO / 16;                   // 8 (DO=128) or 4 (DO=64)
    constexpr int TPW = (NT + 3) / 4;             // tiles per wave: 2 or 1
#pragma unroll
    for (int tt = 0; tt < TPW; ++tt) {
        int t = wave + tt * 4;
        f32x4 acc = {0.f, 0.f, 0.f, 0.f};
#pragma unroll
        for (int ks = 0; ks < 4; ++ks) {
            shortx8 b = *(const shortx8*)&WT[(size_t)(t * 16 + lrow) * 128 + ks * 32 + lk8 * 8];
            acc = __builtin_amdgcn_mfma_f32_16x16x32_bf16(af[ks], b, acc, 0, 0, 0);
        }
#pragma unroll
        for (int r = 0; r < 4; ++r) {
            int orow = nb0 + lk8 * 4 + r;
            out16[(size_t)orow * DO + t * 16 + lrow] = f2bf(acc[r]);
        }
    }
}

// ---------------- FUSED: agg DO=64 (+b3) -> pool via block-partial atomics -------
// 4 waves = 4 consecutive nodes (batch sorted -> ~1.06 distinct graphs/block).
// Node results staged in LDS; 64 threads run-length-group by graph and emit
// ONE atomicAdd per (graph,channel) per block (~212K total, 32K L2-resident
// addrs, ~7 adds each). Empty graphs never touched -> stay 0 (= reference).
__global__ __launch_bounds__(256) void k_agg64pool(
        const unsigned short* __restrict__ h16,
        const int* __restrict__ cnt, const int* __restrict__ csr_idx,
        const float* __restrict__ dinv, const float* __restrict__ b,
        const int* __restrict__ batch, const int* __restrict__ gstart,
        const int* __restrict__ gend, float* __restrict__ out) {
    __shared__ float sm[4][64];

    int tid = threadIdx.x;
    int wave = tid >> 6, lane = tid & 63;
    int nb0 = blockIdx.x * 4;        // NN % 4 == 0 -> all blocks full
    int wid = nb0 + wave;
    int oct = lane >> 3;             // 8 edge streams
    int l8 = lane & 7;               // 8 lanes x 8 bf16 ch = 64 ch
    int n = min(cnt[wid], SLOT);
    float dv = dinv[wid];

    int rec = 0; float wl = 0.f;
    if (lane < n) {
        rec = csr_idx[wid * SLOT + lane];
        wl = dv * dinv[rec];
    }

    const uint4* h4 = (const uint4*)h16;
    f32x2 c0 = {0.f, 0.f}, c1 = {0.f, 0.f}, c2 = {0.f, 0.f}, c3 = {0.f, 0.f};

    int jb_end = (n + 15) & ~15;
    for (int jb = 0; jb < jb_end; jb += 16) {
        int j0 = jb + oct;           // j0, j0+8 both < jb_end <= 64
        int s0 = __shfl(rec, j0);
        int s1 = __shfl(rec, j0 + 8);
        float w0 = __shfl(wl, j0);
        float w1 = __shfl(wl, j0 + 8);
        uint4 v0 = h4[(size_t)s0 * 8 + l8];
        uint4 v1 = h4[(size_t)s1 * 8 + l8];
        f32x2 w0v = {w0, w0}, w1v = {w1, w1};
        pkfma(c0, bfpair(v0.x), w0v); pkfma(c1, bfpair(v0.y), w0v);
        pkfma(c2, bfpair(v0.z), w0v); pkfma(c3, bfpair(v0.w), w0v);
        pkfma(c0, bfpair(v1.x), w1v); pkfma(c1, bfpair(v1.y), w1v);
        pkfma(c2, bfpair(v1.z), w1v); pkfma(c3, bfpair(v1.w), w1v);
    }

    c0.x += __shfl_down(c0.x, 32); c0.y += __shfl_down(c0.y, 32);
    c1.x += __shfl_down(c1.x, 32); c1.y += __shfl_down(c1.y, 32);
    c2.x += __shfl_down(c2.x, 32); c2.y += __shfl_down(c2.y, 32);
    c3.x += __shfl_down(c3.x, 32); c3.y += __shfl_down(c3.y, 32);
    c0.x += __shfl_down(c0.x, 16); c0.y += __shfl_down(c0.y, 16);
    c1.x += __shfl_down(c1.x, 16); c1.y += __shfl_down(c1.y, 16);
    c2.x += __shfl_down(c2.x, 16); c2.y += __shfl_down(c2.y, 16);
    c3.x += __shfl_down(c3.x, 16); c3.y += __shfl_down(c3.y, 16);
    c0.x += __shfl_down(c0.x, 8);  c0.y += __shfl_down(c0.y, 8);
    c1.x += __shfl_down(c1.x, 8);  c1.y += __shfl_down(c1.y, 8);
    c2.x += __shfl_down(c2.x, 8);  c2.y += __shfl_down(c2.y, 8);
    c3.x += __shfl_down(c3.x, 8);  c3.y += __shfl_down(c3.y, 8);
    if (lane < 8) {
        float d2 = dv * dv;
        uint4 hv = h4[(size_t)wid * 8 + l8];
        float4 b0 = *(const float4*)&b[l8 * 8];
        float4 b1 = *(const float4*)&b[l8 * 8 + 4];
        f32x2 d2v = {d2, d2};
        pkfma(c0, bfpair(hv.x), d2v);
        pkfma(c1, bfpair(hv.y), d2v);
        pkfma(c2, bfpair(hv.z), d2v);
        pkfma(c3, bfpair(hv.w), d2v);
        sm[wave][l8 * 8 + 0] = c0.x + b0.x;
        sm[wave][l8 * 8 + 1] = c0.y + b0.y;
        sm[wave][l8 * 8 + 2] = c1.x + b0.z;
        sm[wave][l8 * 8 + 3] = c1.y + b0.w;
        sm[wave][l8 * 8 + 4] = c2.x + b1.x;
        sm[wave][l8 * 8 + 5] = c2.y + b1.y;
        sm[wave][l8 * 8 + 6] = c3.x + b1.z;
        sm[wave][l8 * 8 + 7] = c3.y + b1.w;
    }
    __syncthreads();

    if (tid < 64) {
        int ch = tid;
        int cur = batch[nb0];
        float acc = 0.f;
#pragma unroll
        for (int w = 0; w < 4; ++w) {
            int g = batch[nb0 + w];
            if (g != cur) {
                float inv = 1.0f / fmaxf((float)(gend[cur] - gstart[cur]), 1.0f);
                atomicAdd(&out[(size_t)cur * 64 + ch], acc * inv);
                acc = 0.f;
                cur = g;
            }
            acc += sm[w][ch];
        }
        float inv = 1.0f / fmaxf((float)(gend[cur] - gstart[cur]), 1.0f);
        atomicAdd(&out[(size_t)cur * 64 + ch], acc * inv);
    }
}

extern "C" void kernel_launch(void* const* d_in, const int* in_sizes, int n_in,
                              void* d_out, int out_size, void* d_ws, size_t ws_size,
                              hipStream_t stream) {
    const float* x     = (const float*)d_in[0];
    const int*   ei    = (const int*)d_in[1];
    const int*   batch = (const int*)d_in[2];
    const float* W1 = (const float*)d_in[3];
    const float* b1 = (const float*)d_in[4];
    const float* W2 = (const float*)d_in[5];
    const float* b2 = (const float*)d_in[6];
    const float* W3 = (const float*)d_in[7];
    const float* b3 = (const float*)d_in[8];
    float* out = (float*)d_out;

    const int* src = ei;
    const int* dst = ei + NE;

    char* p = (char*)d_ws;
    auto alloc = [&](size_t nbytes) -> void* {
        void* r = (void*)p;
        p += (nbytes + 255) & ~((size_t)255);
        return r;
    };
    // total ~51.9 MB (within proven envelope)
    int*   ctrl    = (int*)alloc((size_t)NCTRL * 4);
    int*   cursor  = ctrl;
    int*   gstart  = ctrl + NBUCK;
    int*   gend    = ctrl + NBUCK + GG;
    int*   cnt     = (int*)alloc((size_t)NN * 4);
    float* dinv    = (float*)alloc((size_t)NN * 4);
    int*   csr_idx = (int*)alloc((size_t)NN * SLOT * 4);
    unsigned short* bufA16 = (unsigned short*)alloc((size_t)NN * 128 * 2);   // gemm1 out / gemm3 out
    float* bufB    = (float*)alloc((size_t)NN * 128 * 4);                    // staging
    unsigned short* WT1 = (unsigned short*)alloc(128 * 128 * 2);
    unsigned short* WT2 = (unsigned short*)alloc(128 * 128 * 2);
    unsigned short* WT3 = (unsigned short*)alloc(128 * 64 * 2);
    // aliases on bufB (stream order makes these safe):
    unsigned* ebuf = (unsigned*)bufB;                 // build staging, dead after binB
    unsigned short* bufC16 = (unsigned short*)bufB;   // gemm2 out, dead after fused23

    const int B = 256;
    auto nb = [](long long n, int b) { return (int)((n + b - 1) / b); };
    const int fused_grid = NN / 16;                   // 3125 (NN % 16 == 0)
    const int aggpool_grid = NN / 4;                  // 12500 (NN % 4 == 0)

    // --- prep: weights (bf16 col-major) + ctrl zero + out zero ---
    k_wprep<<<128, 256, 0, stream>>>(W1, W2, W3, WT1, WT2, WT3, ctrl, out);

    // --- binA (edge binning) || gemm1 (x @ W1), overlapped ---
    k_binA_gemm1<<<NBLK_A + GEMM_BLKS, 256, 0, stream>>>(src, dst, cursor, ebuf,
                                                         x, WT1, bufA16);

    // --- build phase B (direct-write CSR) ---
    k_binB<<<NBUCK, 256, 0, stream>>>(cursor, ebuf, cnt, csr_idx, dinv, batch,
                                      gstart, gend);

    // --- fused: agg1(+b1,relu) -> gemm2 ---
    k_agg_gemm<128><<<fused_grid, 256, 0, stream>>>(bufA16, cnt, csr_idx, dinv,
                                                    b1, WT2, bufC16);

    // --- fused: agg2(+b2,relu) -> gemm3 ---
    k_agg_gemm<64><<<fused_grid, 256, 0, stream>>>(bufC16, cnt, csr_idx, dinv,
                                                   b2, WT3, bufA16);

    // --- fused: agg3(+b3) -> global mean pool (block-partial atomics) ---
    k_agg64pool<<<aggpool_grid, B, 0, stream>>>(bufA16, cnt, csr_idx, dinv, b3,
                                                batch, gstart, gend, out);
}